// Round 14
// baseline (31314.304 us; speedup 1.0000x reference)
//
#include <hip/hip_runtime.h>

#define HH 512
#define OO 256
#define BB 64
#define SS 1024
#define TT 256
#define KK 1280   // H(ctx) + O(target) + H(h)

typedef __attribute__((ext_vector_type(8))) short bh8;
typedef __attribute__((ext_vector_type(8))) _Float16 hf8;
typedef __attribute__((ext_vector_type(4))) float fx4;
typedef unsigned short ushort_t;

__device__ __forceinline__ ushort_t f2bf(float x) {
    union { float f; unsigned int u; } v; v.f = x;
    unsigned int r = v.u + 0x7fffu + ((v.u >> 16) & 1u);
    return (ushort_t)(r >> 16);
}
__device__ __forceinline__ float bf2f(ushort_t s) {
    union { unsigned int u; float f; } z; z.u = ((unsigned int)s) << 16; return z.f;
}

// Pack W_cat = [W_ih | W_hh] (j-permuted; see round-0 comment) into MFMA
// B-fragment-major bf16 hi/lo split: W = hi + lo, lo = bf16(W - f32(hi)).
__global__ void prep_weights(const float* __restrict__ W_ih,
                             const float* __restrict__ W_hh,
                             ushort_t* __restrict__ wfH,
                             ushort_t* __restrict__ wfL) {
    int g = blockIdx.x * 256 + threadIdx.x;     // 64*40*2*64 = 327680 groups
    if (g >= 64 * 40 * 2 * 64) return;
    int lane = g & 63;
    int nt = (g >> 6) & 1;
    int kk = (g >> 7) % 40;
    int ht = (g >> 7) / 40;
    int c = nt * 16 + (lane & 15);
    int gate = c >> 3, rr = c & 7;
    int j = gate * 512 + ht * 8 + rr;
    int kbase = kk * 32 + (lane >> 4) * 8;
    ushort_t* dh = wfH + (size_t)g * 8;
    ushort_t* dl = wfL + (size_t)g * 8;
#pragma unroll
    for (int r = 0; r < 8; ++r) {
        int k = kbase + r;
        float v = (k < 768) ? W_ih[(size_t)j * 768 + k]
                            : W_hh[(size_t)j * 512 + (k - 768)];
        ushort_t hi = f2bf(v);
        dh[r] = hi;
        dl[r] = f2bf(v - bf2f(hi));
    }
}

__global__ void prep_misc(const float* __restrict__ hidden,
                          const float* __restrict__ cell,
                          float* __restrict__ h, float* __restrict__ c) {
    const int total = 32768 + 32768;
    for (int i = blockIdx.x * 256 + threadIdx.x; i < total; i += gridDim.x * 256) {
        if (i < 32768) h[i] = hidden[i];
        else           c[i - 32768] = cell[i - 32768];
    }
}

// One-time fp32 -> fp16 convert of encoder_outputs (33.5M elems, 8/thread).
__global__ void prep_ench(const float* __restrict__ enc,
                          _Float16* __restrict__ ench) {
    const size_t i = ((size_t)blockIdx.x * 256 + threadIdx.x) * 8;
    const float4 a = *(const float4*)(enc + i);
    const float4 b = *(const float4*)(enc + i + 4);
    hf8 o;
    o[0] = (_Float16)a.x; o[1] = (_Float16)a.y;
    o[2] = (_Float16)a.z; o[3] = (_Float16)a.w;
    o[4] = (_Float16)b.x; o[5] = (_Float16)b.y;
    o[6] = (_Float16)b.z; o[7] = (_Float16)b.w;
    *(hf8*)(ench + i) = o;
}

// FC for one (b, oq) unit; fp32 W_fc rows (summation order as R4-R9).
__device__ __forceinline__ void fc_unit(int v, int tprev,
                                        const float* __restrict__ h,
                                        const float* __restrict__ W_fc,
                                        const float* __restrict__ b_fc,
                                        float* __restrict__ out,
                                        float (*shacc)[64]) {
    const int tid = threadIdx.x;
    const int b = v >> 2, oq = v & 3;
    const int ol = tid & 63, kq = tid >> 6;
    const int o = oq * 64 + ol;
    float acc = 0.f;
    const float* hp = h + b * HH + kq * 128;
    const float* wp = W_fc + (size_t)o * HH + kq * 128;
#pragma unroll 8
    for (int k2 = 0; k2 < 128; ++k2) acc += hp[k2] * wp[k2];
    shacc[kq][ol] = acc;
    __syncthreads();
    if (tid < 64) {
        float vv = shacc[0][tid] + shacc[1][tid]
                 + shacc[2][tid] + shacc[3][tid] + b_fc[oq * 64 + tid];
        out[((size_t)b * TT + tprev) * OO + oq * 64 + tid] = vv;
    }
}

// K1 (R9's step_attnp, fp16 path, verbatim): blocks 0..1023 attention partial
// (b, 64-row chunk) -> pm/pl/pctx; blocks 1024..1279 FC(t-1). Fence-free.
__global__ void __launch_bounds__(256)
step_attnp(int t, const _Float16* __restrict__ ench,
           const float* __restrict__ h,
           float* __restrict__ pm, float* __restrict__ pl,
           float* __restrict__ pctx,
           const float* __restrict__ W_fc, const float* __restrict__ b_fc,
           float* __restrict__ out) {
    const int tid = threadIdx.x;
    const int lane = tid & 63;
    const int w = tid >> 6;

    __shared__ union {
        struct { float m[4]; float l[4]; float ctx[4][512]; } a;
        struct { float acc[4][64]; } o;
    } sh;

    const int u = blockIdx.x;
    if (u < 1024) {
        const int b = u >> 4, ch = u & 15;
        float m = -3.0e38f, l = 0.f;
        const float* hb = h + b * HH + lane * 8;
        const float4 h0 = *(const float4*)hb;
        const float4 h1 = *(const float4*)(hb + 4);
        float cx[8];
#pragma unroll
        for (int j = 0; j < 8; ++j) cx[j] = 0.f;
        const _Float16* er =
            ench + ((size_t)(b * SS + ch * 64 + w * 16)) * HH + lane * 8;
        for (int rp = 0; rp < 8; ++rp) {
            const hf8 ev = *(const hf8*)er;
            const hf8 fv = *(const hf8*)(er + HH);
            float e[8], f[8];
#pragma unroll
            for (int j = 0; j < 8; ++j) {
                e[j] = (float)ev[j];
                f[j] = (float)fv[j];
            }
            float dA = e[0]*h0.x + e[1]*h0.y + e[2]*h0.z + e[3]*h0.w
                     + e[4]*h1.x + e[5]*h1.y + e[6]*h1.z + e[7]*h1.w;
            float dB = f[0]*h0.x + f[1]*h0.y + f[2]*h0.z + f[3]*h0.w
                     + f[4]*h1.x + f[5]*h1.y + f[6]*h1.z + f[7]*h1.w;
#pragma unroll
            for (int off = 32; off; off >>= 1) {
                dA += __shfl_xor(dA, off);
                dB += __shfl_xor(dB, off);
            }
            const float mx = fmaxf(dA, dB);
            if (mx > m) {                      // wave-uniform branch
                const float fs = __expf(m - mx);
                l *= fs;
#pragma unroll
                for (int j = 0; j < 8; ++j) cx[j] *= fs;
                m = mx;
            }
            const float pA = __expf(dA - m);
            const float pB = __expf(dB - m);
            l += pA + pB;
#pragma unroll
            for (int j = 0; j < 8; ++j) cx[j] += pA * e[j] + pB * f[j];
            er += 2 * HH;
        }
        if (lane == 0) { sh.a.m[w] = m; sh.a.l[w] = l; }
        *(float4*)&sh.a.ctx[w][lane * 8]     = make_float4(cx[0], cx[1], cx[2], cx[3]);
        *(float4*)&sh.a.ctx[w][lane * 8 + 4] = make_float4(cx[4], cx[5], cx[6], cx[7]);
        __syncthreads();
        // block-level combine of the 4 wave partials
        float M = fmaxf(fmaxf(sh.a.m[0], sh.a.m[1]), fmaxf(sh.a.m[2], sh.a.m[3]));
        float wg[4]; float ls = 0.f;
#pragma unroll
        for (int q = 0; q < 4; ++q) { wg[q] = __expf(sh.a.m[q] - M); ls += wg[q] * sh.a.l[q]; }
        const int hh = tid * 2;
        float v0 = wg[0] * sh.a.ctx[0][hh] + wg[1] * sh.a.ctx[1][hh]
                 + wg[2] * sh.a.ctx[2][hh] + wg[3] * sh.a.ctx[3][hh];
        float v1 = wg[0] * sh.a.ctx[0][hh + 1] + wg[1] * sh.a.ctx[1][hh + 1]
                 + wg[2] * sh.a.ctx[2][hh + 1] + wg[3] * sh.a.ctx[3][hh + 1];
        float* pc = pctx + ((size_t)(b * 16 + ch)) * HH;
        *(float2*)(pc + hh) = make_float2(v0, v1);
        if (tid == 0) { pm[b * 16 + ch] = M; pl[b * 16 + ch] = ls; }
    } else if (t > 0) {
        fc_unit(u - 1024, t - 1, h, W_fc, b_fc, out, sh.o.acc);
    }
}

// K2: gates MFMA with INLINE 16-partial softmax combine (no xb, no combine
// kernel). ctx A-frag = sum_q cw[b][q]*pctx[b*16+q][k], split to bf16 hi/lo;
// target/h regions split inline (R11 gates4 pattern, proven). Reads hin,
// writes hout (double buffer).
__global__ void __launch_bounds__(256)
step_gates16(int t, const float* __restrict__ pm, const float* __restrict__ pl,
             const float* __restrict__ pctx,
             const float* __restrict__ target, const float* __restrict__ hin,
             const ushort_t* __restrict__ wfH, const ushort_t* __restrict__ wfL,
             const float* __restrict__ b_ih, const float* __restrict__ b_hh,
             float* __restrict__ hout, float* __restrict__ c) {
    const int tid = threadIdx.x;
    const int lane = tid & 63;
    const int w = tid >> 6;
    __shared__ float g[64][32];
    __shared__ float cw[64][16];

    // per-b combine coefficients (normalization folded in)
    if (tid < 64) {
        const int b = tid;
        float pmv[16];
        float M = -3.0e38f;
#pragma unroll
        for (int q = 0; q < 16; ++q) { pmv[q] = pm[b * 16 + q]; M = fmaxf(M, pmv[q]); }
        float wq[16]; float lsb = 0.f;
#pragma unroll
        for (int q = 0; q < 16; ++q) {
            wq[q] = __expf(pmv[q] - M);
            lsb += wq[q] * pl[b * 16 + q];
        }
        const float inv = 1.0f / lsb;
#pragma unroll
        for (int q = 0; q < 16; ++q) cw[b][q] = wq[q] * inv;
    }
    __syncthreads();

    const int ht = blockIdx.x;
    fx4 a0 = {0, 0, 0, 0}, a1 = {0, 0, 0, 0};
    const int bro = 16 * w + (lane & 15);
    const int kg = lane >> 4;
    const size_t wbase = (size_t)ht * 40 * 2 * 512;
    float cwr[16];
#pragma unroll
    for (int q = 0; q < 16; ++q) cwr[q] = cw[bro][q];
    const float* pcb = pctx + (size_t)bro * 16 * 512;

#define GATES_MFMA_STEP(kkv)                                                   \
    {                                                                          \
        bh8 b0h = *(const bh8*)(wfH + wbase + ((kkv) * 2 + 0) * 512 + lane*8); \
        bh8 b1h = *(const bh8*)(wfH + wbase + ((kkv) * 2 + 1) * 512 + lane*8); \
        bh8 b0l = *(const bh8*)(wfL + wbase + ((kkv) * 2 + 0) * 512 + lane*8); \
        bh8 b1l = *(const bh8*)(wfL + wbase + ((kkv) * 2 + 1) * 512 + lane*8); \
        a0 = __builtin_amdgcn_mfma_f32_16x16x32_bf16(avh, b0h, a0, 0, 0, 0);   \
        a0 = __builtin_amdgcn_mfma_f32_16x16x32_bf16(avl, b0h, a0, 0, 0, 0);   \
        a0 = __builtin_amdgcn_mfma_f32_16x16x32_bf16(avh, b0l, a0, 0, 0, 0);   \
        a1 = __builtin_amdgcn_mfma_f32_16x16x32_bf16(avh, b1h, a1, 0, 0, 0);   \
        a1 = __builtin_amdgcn_mfma_f32_16x16x32_bf16(avl, b1h, a1, 0, 0, 0);   \
        a1 = __builtin_amdgcn_mfma_f32_16x16x32_bf16(avh, b1l, a1, 0, 0, 0);   \
    }

    // ctx region: kk 0..15, k0 = kk*32 + kg*8
    for (int kk = 0; kk < 16; ++kk) {
        const int k0 = kk * 32 + kg * 8;
        float af[8];
#pragma unroll
        for (int j = 0; j < 8; ++j) af[j] = 0.f;
#pragma unroll
        for (int q = 0; q < 16; ++q) {
            const float* pq = pcb + q * 512 + k0;
            const float4 v0 = *(const float4*)pq;
            const float4 v1 = *(const float4*)(pq + 4);
            const float cq = cwr[q];
            af[0] += cq * v0.x; af[1] += cq * v0.y;
            af[2] += cq * v0.z; af[3] += cq * v0.w;
            af[4] += cq * v1.x; af[5] += cq * v1.y;
            af[6] += cq * v1.z; af[7] += cq * v1.w;
        }
        bh8 avh, avl;
#pragma unroll
        for (int j = 0; j < 8; ++j) {
            const ushort_t hi = f2bf(af[j]);
            avh[j] = (short)hi;
            avl[j] = (short)f2bf(af[j] - bf2f(hi));
        }
        GATES_MFMA_STEP(kk)
    }
    // target region: kk 16..23
    {
        const float* tb = target + ((size_t)bro * TT + t) * OO + kg * 8 - 512;
        for (int kk = 16; kk < 24; ++kk) {
            const float* tp = tb + kk * 32;
            bh8 avh, avl;
#pragma unroll
            for (int j = 0; j < 8; ++j) {
                const float s = tp[j];
                const ushort_t hi = f2bf(s);
                avh[j] = (short)hi;
                avl[j] = (short)f2bf(s - bf2f(hi));
            }
            GATES_MFMA_STEP(kk)
        }
    }
    // h region: kk 24..39
    {
        const float* hb = hin + bro * HH + kg * 8 - 768;
        for (int kk = 24; kk < 40; ++kk) {
            const float* hp = hb + kk * 32;
            bh8 avh, avl;
#pragma unroll
            for (int j = 0; j < 8; ++j) {
                const float s = hp[j];
                const ushort_t hi = f2bf(s);
                avh[j] = (short)hi;
                avl[j] = (short)f2bf(s - bf2f(hi));
            }
            GATES_MFMA_STEP(kk)
        }
    }
#undef GATES_MFMA_STEP

    const int crow = (lane >> 4) * 4;
#pragma unroll
    for (int r = 0; r < 4; ++r) {
        g[16 * w + crow + r][lane & 15]        = a0[r];
        g[16 * w + crow + r][16 + (lane & 15)] = a1[r];
    }
    __syncthreads();
#pragma unroll
    for (int p = 0; p < 2; ++p) {
        const int idx = tid * 2 + p;
        const int b = idx >> 3, r = idx & 7;
        const int hidx = ht * 8 + r;
        float gi = g[b][r]      + b_ih[hidx]        + b_hh[hidx];
        float gf = g[b][8 + r]  + b_ih[512 + hidx]  + b_hh[512 + hidx];
        float gg = g[b][16 + r] + b_ih[1024 + hidx] + b_hh[1024 + hidx];
        float go = g[b][24 + r] + b_ih[1536 + hidx] + b_hh[1536 + hidx];
        float ig = 1.f / (1.f + __expf(-gi));
        float fg = 1.f / (1.f + __expf(-gf));
        float g2 = tanhf(gg);
        float og = 1.f / (1.f + __expf(-go));
        float cn = fg * c[b * HH + hidx] + ig * g2;
        float hn = og * tanhf(cn);
        c[b * HH + hidx] = cn;
        hout[b * HH + hidx] = hn;
    }
}

__global__ void __launch_bounds__(256)
fc_final(const float* __restrict__ h, const float* __restrict__ W_fc,
         const float* __restrict__ b_fc, float* __restrict__ out) {
    __shared__ float acc[4][64];
    fc_unit(blockIdx.x, TT - 1, h, W_fc, b_fc, out, acc);
}

extern "C" void kernel_launch(void* const* d_in, const int* in_sizes, int n_in,
                              void* d_out, int out_size, void* d_ws, size_t ws_size,
                              hipStream_t stream) {
    const float* enc    = (const float*)d_in[0];
    const float* hidden = (const float*)d_in[1];
    const float* cellp  = (const float*)d_in[2];
    const float* target = (const float*)d_in[3];
    const float* W_ih   = (const float*)d_in[4];
    const float* W_hh   = (const float*)d_in[5];
    const float* b_ih   = (const float*)d_in[6];
    const float* b_hh   = (const float*)d_in[7];
    const float* W_fc   = (const float*)d_in[8];
    const float* b_fc   = (const float*)d_in[9];
    float* out = (float*)d_out;

    char* base = (char*)d_ws;
    float* hA          = (float*)(base + 0);                 // 131,072 B
    float* hB          = (float*)(base + 131072);            // 131,072 B
    float* c           = (float*)(base + 262144);            // 131,072 B
    ushort_t* wfH      = (ushort_t*)(base + 393216);         // 5,242,880 B
    ushort_t* wfL      = (ushort_t*)(base + 5636096);        // 5,242,880 B
    float* pm          = (float*)(base + 10878976);          // 4,096 B
    float* pl          = (float*)(base + 10883072);          // 4,096 B
    float* pctx        = (float*)(base + 10887168);          // 2,097,152 B
    _Float16* ench     = (_Float16*)(base + 12984320);       // 67,108,864 B
    // end: 80,093,184 B  (< 80,289,792 proven available in R9)

    prep_weights<<<dim3(1280), dim3(256), 0, stream>>>(W_ih, W_hh, wfH, wfL);
    prep_misc<<<dim3(256), dim3(256), 0, stream>>>(hidden, cellp, hA, c);
    prep_ench<<<dim3(16384), dim3(256), 0, stream>>>(enc, ench);

    for (int t = 0; t < TT; ++t) {
        float* hcur = (t & 1) ? hB : hA;
        float* hnxt = (t & 1) ? hA : hB;
        step_attnp<<<dim3(1280), dim3(256), 0, stream>>>(
            t, ench, hcur, pm, pl, pctx, W_fc, b_fc, out);
        step_gates16<<<dim3(64), dim3(256), 0, stream>>>(
            t, pm, pl, pctx, target, hcur, wfH, wfL, b_ih, b_hh, hnxt, c);
    }
    // t=255 (odd) wrote hnxt = hA
    fc_final<<<dim3(256), dim3(256), 0, stream>>>(hA, W_fc, b_fc, out);
}

// Round 15
// 10647.742 us; speedup vs baseline: 2.9409x; 2.9409x over previous
//
#include <hip/hip_runtime.h>

#define HH 512
#define OO 256
#define BB 64
#define SS 1024
#define TT 256
#define KK 1280   // H(ctx) + O(target) + H(h)

typedef __attribute__((ext_vector_type(8))) short bh8;
typedef __attribute__((ext_vector_type(8))) _Float16 hf8;
typedef __attribute__((ext_vector_type(4))) float fx4;
typedef unsigned short ushort_t;

__device__ __forceinline__ ushort_t f2bf(float x) {
    union { float f; unsigned int u; } v; v.f = x;
    unsigned int r = v.u + 0x7fffu + ((v.u >> 16) & 1u);
    return (ushort_t)(r >> 16);
}
__device__ __forceinline__ float bf2f(ushort_t s) {
    union { unsigned int u; float f; } z; z.u = ((unsigned int)s) << 16; return z.f;
}

// Pack W_cat = [W_ih | W_hh] (j-permuted; see round-0 comment) into MFMA
// B-fragment-major bf16 hi/lo split: W = hi + lo, lo = bf16(W - f32(hi)).
__global__ void prep_weights(const float* __restrict__ W_ih,
                             const float* __restrict__ W_hh,
                             ushort_t* __restrict__ wfH,
                             ushort_t* __restrict__ wfL) {
    int g = blockIdx.x * 256 + threadIdx.x;     // 64*40*2*64 = 327680 groups
    if (g >= 64 * 40 * 2 * 64) return;
    int lane = g & 63;
    int nt = (g >> 6) & 1;
    int kk = (g >> 7) % 40;
    int ht = (g >> 7) / 40;
    int c = nt * 16 + (lane & 15);
    int gate = c >> 3, rr = c & 7;
    int j = gate * 512 + ht * 8 + rr;
    int kbase = kk * 32 + (lane >> 4) * 8;
    ushort_t* dh = wfH + (size_t)g * 8;
    ushort_t* dl = wfL + (size_t)g * 8;
#pragma unroll
    for (int r = 0; r < 8; ++r) {
        int k = kbase + r;
        float v = (k < 768) ? W_ih[(size_t)j * 768 + k]
                            : W_hh[(size_t)j * 512 + (k - 768)];
        ushort_t hi = f2bf(v);
        dh[r] = hi;
        dl[r] = f2bf(v - bf2f(hi));
    }
}

// h/c copy + W_fc fp32->fp16 convert.
__global__ void prep_misc(const float* __restrict__ hidden,
                          const float* __restrict__ cell,
                          const float* __restrict__ W_fc,
                          float* __restrict__ h, float* __restrict__ c,
                          _Float16* __restrict__ wfc16) {
    const int total = 32768 + 32768 + 131072;
    for (int i = blockIdx.x * 256 + threadIdx.x; i < total; i += gridDim.x * 256) {
        if (i < 32768)       h[i] = hidden[i];
        else if (i < 65536)  c[i - 32768] = cell[i - 32768];
        else                 wfc16[i - 65536] = (_Float16)W_fc[i - 65536];
    }
}

// One-time fp32 -> fp16 convert of encoder_outputs (33.5M elems, 8/thread).
__global__ void prep_ench(const float* __restrict__ enc,
                          _Float16* __restrict__ ench) {
    const size_t i = ((size_t)blockIdx.x * 256 + threadIdx.x) * 8;
    const float4 a = *(const float4*)(enc + i);
    const float4 b = *(const float4*)(enc + i + 4);
    hf8 o;
    o[0] = (_Float16)a.x; o[1] = (_Float16)a.y;
    o[2] = (_Float16)a.z; o[3] = (_Float16)a.w;
    o[4] = (_Float16)b.x; o[5] = (_Float16)b.y;
    o[6] = (_Float16)b.z; o[7] = (_Float16)b.w;
    *(hf8*)(ench + i) = o;
}

// FC for one (b, oq) unit; fp16 W_fc rows, fp32 accumulate (same order).
__device__ __forceinline__ void fc_unit(int v, int tprev,
                                        const float* __restrict__ h,
                                        const _Float16* __restrict__ wfc16,
                                        const float* __restrict__ b_fc,
                                        float* __restrict__ out,
                                        float (*shacc)[64]) {
    const int tid = threadIdx.x;
    const int b = v >> 2, oq = v & 3;
    const int ol = tid & 63, kq = tid >> 6;
    const int o = oq * 64 + ol;
    float acc = 0.f;
    const float* hp = h + b * HH + kq * 128;
    const _Float16* wp = wfc16 + (size_t)o * HH + kq * 128;
#pragma unroll 8
    for (int k2 = 0; k2 < 128; ++k2) acc += hp[k2] * (float)wp[k2];
    shacc[kq][ol] = acc;
    __syncthreads();
    if (tid < 64) {
        float vv = shacc[0][tid] + shacc[1][tid]
                 + shacc[2][tid] + shacc[3][tid] + b_fc[oq * 64 + tid];
        out[((size_t)b * TT + tprev) * OO + oq * 64 + tid] = vv;
    }
}

// K1: blocks 0..1023 attention partial (b, 64-row chunk) -> pm/pl/pctx(fp16);
// ILP-4 inner loop (4 independent rows per iteration). Blocks 1024..1279
// FC(t-1). Fence-free.
__global__ void __launch_bounds__(256)
step_attnp(int t, const _Float16* __restrict__ ench,
           const float* __restrict__ h,
           float* __restrict__ pm, float* __restrict__ pl,
           _Float16* __restrict__ pctx,
           const _Float16* __restrict__ wfc16, const float* __restrict__ b_fc,
           float* __restrict__ out) {
    const int tid = threadIdx.x;
    const int lane = tid & 63;
    const int w = tid >> 6;

    __shared__ union {
        struct { float m[4]; float l[4]; float ctx[4][512]; } a;
        struct { float acc[4][64]; } o;
    } sh;

    const int u = blockIdx.x;
    if (u < 1024) {
        const int b = u >> 4, ch = u & 15;
        float m = -3.0e38f, l = 0.f;
        const float* hb = h + b * HH + lane * 8;
        const float4 h0 = *(const float4*)hb;
        const float4 h1 = *(const float4*)(hb + 4);
        float cx[8];
#pragma unroll
        for (int j = 0; j < 8; ++j) cx[j] = 0.f;
        const _Float16* er =
            ench + ((size_t)(b * SS + ch * 64 + w * 16)) * HH + lane * 8;
        for (int g4 = 0; g4 < 4; ++g4) {
            // 4 independent rows in flight
            const hf8 v0 = *(const hf8*)er;
            const hf8 v1 = *(const hf8*)(er + HH);
            const hf8 v2 = *(const hf8*)(er + 2 * HH);
            const hf8 v3 = *(const hf8*)(er + 3 * HH);
            float e0[8], e1[8], e2[8], e3[8];
#pragma unroll
            for (int j = 0; j < 8; ++j) {
                e0[j] = (float)v0[j]; e1[j] = (float)v1[j];
                e2[j] = (float)v2[j]; e3[j] = (float)v3[j];
            }
            float d0 = e0[0]*h0.x + e0[1]*h0.y + e0[2]*h0.z + e0[3]*h0.w
                     + e0[4]*h1.x + e0[5]*h1.y + e0[6]*h1.z + e0[7]*h1.w;
            float d1 = e1[0]*h0.x + e1[1]*h0.y + e1[2]*h0.z + e1[3]*h0.w
                     + e1[4]*h1.x + e1[5]*h1.y + e1[6]*h1.z + e1[7]*h1.w;
            float d2 = e2[0]*h0.x + e2[1]*h0.y + e2[2]*h0.z + e2[3]*h0.w
                     + e2[4]*h1.x + e2[5]*h1.y + e2[6]*h1.z + e2[7]*h1.w;
            float d3 = e3[0]*h0.x + e3[1]*h0.y + e3[2]*h0.z + e3[3]*h0.w
                     + e3[4]*h1.x + e3[5]*h1.y + e3[6]*h1.z + e3[7]*h1.w;
#pragma unroll
            for (int off = 32; off; off >>= 1) {
                d0 += __shfl_xor(d0, off);
                d1 += __shfl_xor(d1, off);
                d2 += __shfl_xor(d2, off);
                d3 += __shfl_xor(d3, off);
            }
            const float mx = fmaxf(fmaxf(d0, d1), fmaxf(d2, d3));
            if (mx > m) {                      // wave-uniform branch
                const float fs = __expf(m - mx);
                l *= fs;
#pragma unroll
                for (int j = 0; j < 8; ++j) cx[j] *= fs;
                m = mx;
            }
            const float p0 = __expf(d0 - m);
            const float p1 = __expf(d1 - m);
            const float p2 = __expf(d2 - m);
            const float p3 = __expf(d3 - m);
            l += (p0 + p1) + (p2 + p3);
#pragma unroll
            for (int j = 0; j < 8; ++j)
                cx[j] += p0 * e0[j] + p1 * e1[j] + p2 * e2[j] + p3 * e3[j];
            er += 4 * HH;
        }
        if (lane == 0) { sh.a.m[w] = m; sh.a.l[w] = l; }
        *(float4*)&sh.a.ctx[w][lane * 8]     = make_float4(cx[0], cx[1], cx[2], cx[3]);
        *(float4*)&sh.a.ctx[w][lane * 8 + 4] = make_float4(cx[4], cx[5], cx[6], cx[7]);
        __syncthreads();
        // block-level combine of the 4 wave partials
        float M = fmaxf(fmaxf(sh.a.m[0], sh.a.m[1]), fmaxf(sh.a.m[2], sh.a.m[3]));
        float wg[4]; float ls = 0.f;
#pragma unroll
        for (int q = 0; q < 4; ++q) { wg[q] = __expf(sh.a.m[q] - M); ls += wg[q] * sh.a.l[q]; }
        const int hh = tid * 2;
        float v0 = wg[0] * sh.a.ctx[0][hh] + wg[1] * sh.a.ctx[1][hh]
                 + wg[2] * sh.a.ctx[2][hh] + wg[3] * sh.a.ctx[3][hh];
        float v1 = wg[0] * sh.a.ctx[0][hh + 1] + wg[1] * sh.a.ctx[1][hh + 1]
                 + wg[2] * sh.a.ctx[2][hh + 1] + wg[3] * sh.a.ctx[3][hh + 1];
        _Float16* pc = pctx + ((size_t)(b * 16 + ch)) * HH;
        pc[hh]     = (_Float16)v0;
        pc[hh + 1] = (_Float16)v1;
        if (tid == 0) { pm[b * 16 + ch] = M; pl[b * 16 + ch] = ls; }
    } else if (t > 0) {
        fc_unit(u - 1024, t - 1, h, wfc16, b_fc, out, sh.o.acc);
    }
}

// Fence-free combine: block b merges 16 chunk partials (fp16 pctx) -> xb
// hi/lo (bf16 split), packs target(t) and h.
__global__ void __launch_bounds__(256)
step_combine(int t, const float* __restrict__ target, const float* __restrict__ h,
             const float* __restrict__ pm, const float* __restrict__ pl,
             const _Float16* __restrict__ pctx,
             ushort_t* __restrict__ xbh, ushort_t* __restrict__ xbl) {
    const int tid = threadIdx.x;
    const int b = blockIdx.x;
    float Mb = -3.0e38f;
#pragma unroll
    for (int q2 = 0; q2 < 16; ++q2) Mb = fmaxf(Mb, pm[b * 16 + q2]);
    float wq[16]; float lsb = 0.f;
#pragma unroll
    for (int q2 = 0; q2 < 16; ++q2) {
        wq[q2] = __expf(pm[b * 16 + q2] - Mb);
        lsb += wq[q2] * pl[b * 16 + q2];
    }
    const float inv = 1.0f / lsb;
    const int h2 = tid * 2;
    float s0 = 0.f, s1 = 0.f;
#pragma unroll
    for (int q2 = 0; q2 < 16; ++q2) {
        const _Float16* pc2 = pctx + ((size_t)(b * 16 + q2)) * HH + h2;
        s0 += wq[q2] * (float)pc2[0];
        s1 += wq[q2] * (float)pc2[1];
    }
    s0 *= inv; s1 *= inv;
    ushort_t a0 = f2bf(s0), a1 = f2bf(s1);
    xbh[b * KK + h2]     = a0;  xbl[b * KK + h2]     = f2bf(s0 - bf2f(a0));
    xbh[b * KK + h2 + 1] = a1;  xbl[b * KK + h2 + 1] = f2bf(s1 - bf2f(a1));
    if (tid < 128) {
        const float* tg = target + ((size_t)b * TT + t) * OO + tid * 2;
        ushort_t t0 = f2bf(tg[0]), t1 = f2bf(tg[1]);
        xbh[b * KK + 512 + tid * 2]     = t0;
        xbh[b * KK + 512 + tid * 2 + 1] = t1;
        xbl[b * KK + 512 + tid * 2]     = f2bf(tg[0] - bf2f(t0));
        xbl[b * KK + 512 + tid * 2 + 1] = f2bf(tg[1] - bf2f(t1));
    }
    const float hv0 = h[b * HH + h2], hv1 = h[b * HH + h2 + 1];
    ushort_t g0 = f2bf(hv0), g1 = f2bf(hv1);
    xbh[b * KK + 768 + h2]     = g0;  xbl[b * KK + 768 + h2]     = f2bf(hv0 - bf2f(g0));
    xbh[b * KK + 768 + h2 + 1] = g1;  xbl[b * KK + 768 + h2 + 1] = f2bf(hv1 - bf2f(g1));
}

// One block per h-tile: split-bf16 gates GEMM (xh*Wh + xl*Wh + xh*Wl) + cell.
// (R9 verbatim.)
__global__ void __launch_bounds__(256)
step_gates(const ushort_t* __restrict__ xbh,
           const ushort_t* __restrict__ xbl,
           const ushort_t* __restrict__ wfH,
           const ushort_t* __restrict__ wfL,
           const float* __restrict__ b_ih, const float* __restrict__ b_hh,
           float* __restrict__ h, float* __restrict__ c) {
    const int tid = threadIdx.x;
    const int lane = tid & 63;
    const int w = tid >> 6;
    __shared__ float g[64][32];

    const int ht = blockIdx.x;
    fx4 a0 = {0, 0, 0, 0}, a1 = {0, 0, 0, 0};
    const int bro = 16 * w + (lane & 15);
    const int kg = lane >> 4;
    const size_t wbase = (size_t)ht * 40 * 2 * 512;
    for (int kk = 0; kk < 40; ++kk) {
        const size_t aoff = (size_t)bro * KK + kk * 32 + kg * 8;
        bh8 avh = *(const bh8*)(xbh + aoff);
        bh8 avl = *(const bh8*)(xbl + aoff);
        bh8 b0h = *(const bh8*)(wfH + wbase + (kk * 2 + 0) * 512 + lane * 8);
        bh8 b1h = *(const bh8*)(wfH + wbase + (kk * 2 + 1) * 512 + lane * 8);
        bh8 b0l = *(const bh8*)(wfL + wbase + (kk * 2 + 0) * 512 + lane * 8);
        bh8 b1l = *(const bh8*)(wfL + wbase + (kk * 2 + 1) * 512 + lane * 8);
        a0 = __builtin_amdgcn_mfma_f32_16x16x32_bf16(avh, b0h, a0, 0, 0, 0);
        a0 = __builtin_amdgcn_mfma_f32_16x16x32_bf16(avl, b0h, a0, 0, 0, 0);
        a0 = __builtin_amdgcn_mfma_f32_16x16x32_bf16(avh, b0l, a0, 0, 0, 0);
        a1 = __builtin_amdgcn_mfma_f32_16x16x32_bf16(avh, b1h, a1, 0, 0, 0);
        a1 = __builtin_amdgcn_mfma_f32_16x16x32_bf16(avl, b1h, a1, 0, 0, 0);
        a1 = __builtin_amdgcn_mfma_f32_16x16x32_bf16(avh, b1l, a1, 0, 0, 0);
    }
    const int crow = (lane >> 4) * 4;
#pragma unroll
    for (int r = 0; r < 4; ++r) {
        g[16 * w + crow + r][lane & 15]        = a0[r];
        g[16 * w + crow + r][16 + (lane & 15)] = a1[r];
    }
    __syncthreads();
#pragma unroll
    for (int p = 0; p < 2; ++p) {
        const int idx = tid * 2 + p;
        const int b = idx >> 3, r = idx & 7;
        const int hidx = ht * 8 + r;
        float gi = g[b][r]      + b_ih[hidx]        + b_hh[hidx];
        float gf = g[b][8 + r]  + b_ih[512 + hidx]  + b_hh[512 + hidx];
        float gg = g[b][16 + r] + b_ih[1024 + hidx] + b_hh[1024 + hidx];
        float go = g[b][24 + r] + b_ih[1536 + hidx] + b_hh[1536 + hidx];
        float ig = 1.f / (1.f + __expf(-gi));
        float fg = 1.f / (1.f + __expf(-gf));
        float g2 = tanhf(gg);
        float og = 1.f / (1.f + __expf(-go));
        float cn = fg * c[b * HH + hidx] + ig * g2;
        float hn = og * tanhf(cn);
        c[b * HH + hidx] = cn;
        h[b * HH + hidx] = hn;
    }
}

__global__ void __launch_bounds__(256)
fc_final(const float* __restrict__ h, const _Float16* __restrict__ wfc16,
         const float* __restrict__ b_fc, float* __restrict__ out) {
    __shared__ float acc[4][64];
    fc_unit(blockIdx.x, TT - 1, h, wfc16, b_fc, out, acc);
}

extern "C" void kernel_launch(void* const* d_in, const int* in_sizes, int n_in,
                              void* d_out, int out_size, void* d_ws, size_t ws_size,
                              hipStream_t stream) {
    const float* enc    = (const float*)d_in[0];
    const float* hidden = (const float*)d_in[1];
    const float* cellp  = (const float*)d_in[2];
    const float* target = (const float*)d_in[3];
    const float* W_ih   = (const float*)d_in[4];
    const float* W_hh   = (const float*)d_in[5];
    const float* b_ih   = (const float*)d_in[6];
    const float* b_hh   = (const float*)d_in[7];
    const float* W_fc   = (const float*)d_in[8];
    const float* b_fc   = (const float*)d_in[9];
    float* out = (float*)d_out;

    char* base = (char*)d_ws;
    float* h            = (float*)(base + 0);                  // 131,072 B
    float* c            = (float*)(base + 131072);             // 131,072 B
    ushort_t* wfH       = (ushort_t*)(base + 262144);          // 5,242,880 B
    ushort_t* wfL       = (ushort_t*)(base + 5505024);         // 5,242,880 B
    ushort_t* xbh       = (ushort_t*)(base + 10747904);        // 163,840 B
    ushort_t* xbl       = (ushort_t*)(base + 10911744);        // 163,840 B
    float* pm           = (float*)(base + 11075584);           // 4,096 B
    float* pl           = (float*)(base + 11079680);           // 4,096 B
    _Float16* wfc16     = (_Float16*)(base + 11083776);        // 262,144 B
    _Float16* pctx      = (_Float16*)(base + 11345920);        // 1,048,576 B
    _Float16* ench      = (_Float16*)(base + 12394496);        // 67,108,864 B
    // end: 79,503,360 B  (< 80,289,792 proven available)

    prep_weights<<<dim3(1280), dim3(256), 0, stream>>>(W_ih, W_hh, wfH, wfL);
    prep_misc<<<dim3(768), dim3(256), 0, stream>>>(hidden, cellp, W_fc, h, c, wfc16);
    prep_ench<<<dim3(16384), dim3(256), 0, stream>>>(enc, ench);

    for (int t = 0; t < TT; ++t) {
        step_attnp<<<dim3(1280), dim3(256), 0, stream>>>(
            t, ench, h, pm, pl, pctx, wfc16, b_fc, out);
        step_combine<<<dim3(64), dim3(256), 0, stream>>>(
            t, target, h, pm, pl, pctx, xbh, xbl);
        step_gates<<<dim3(64), dim3(256), 0, stream>>>(
            xbh, xbl, wfH, wfL, b_ih, b_hh, h, c);
    }
    fc_final<<<dim3(256), dim3(256), 0, stream>>>(h, wfc16, b_fc, out);
}

// Round 16
// 8675.679 us; speedup vs baseline: 3.6094x; 1.2273x over previous
//
#include <hip/hip_runtime.h>

#define HH 512
#define OO 256
#define BB 64
#define SS 1024
#define TT 256
#define KK 1280   // H(ctx) + O(target) + H(h)

typedef __attribute__((ext_vector_type(8))) short bh8;
typedef __attribute__((ext_vector_type(8))) _Float16 hf8;
typedef __attribute__((ext_vector_type(2))) _Float16 h2;
typedef __attribute__((ext_vector_type(4))) float fx4;
typedef unsigned short ushort_t;

__device__ __forceinline__ ushort_t f2bf(float x) {
    union { float f; unsigned int u; } v; v.f = x;
    unsigned int r = v.u + 0x7fffu + ((v.u >> 16) & 1u);
    return (ushort_t)(r >> 16);
}
__device__ __forceinline__ float bf2f(ushort_t s) {
    union { unsigned int u; float f; } z; z.u = ((unsigned int)s) << 16; return z.f;
}

// Pack W_cat = [W_ih | W_hh] (j-permuted; see round-0 comment) into MFMA
// B-fragment-major bf16 hi/lo split: W = hi + lo, lo = bf16(W - f32(hi)).
__global__ void prep_weights(const float* __restrict__ W_ih,
                             const float* __restrict__ W_hh,
                             ushort_t* __restrict__ wfH,
                             ushort_t* __restrict__ wfL) {
    int g = blockIdx.x * 256 + threadIdx.x;     // 64*40*2*64 = 327680 groups
    if (g >= 64 * 40 * 2 * 64) return;
    int lane = g & 63;
    int nt = (g >> 6) & 1;
    int kk = (g >> 7) % 40;
    int ht = (g >> 7) / 40;
    int c = nt * 16 + (lane & 15);
    int gate = c >> 3, rr = c & 7;
    int j = gate * 512 + ht * 8 + rr;
    int kbase = kk * 32 + (lane >> 4) * 8;
    ushort_t* dh = wfH + (size_t)g * 8;
    ushort_t* dl = wfL + (size_t)g * 8;
#pragma unroll
    for (int r = 0; r < 8; ++r) {
        int k = kbase + r;
        float v = (k < 768) ? W_ih[(size_t)j * 768 + k]
                            : W_hh[(size_t)j * 512 + (k - 768)];
        ushort_t hi = f2bf(v);
        dh[r] = hi;
        dl[r] = f2bf(v - bf2f(hi));
    }
}

// h/c copy + W_fc fp32->fp16 convert.
__global__ void prep_misc(const float* __restrict__ hidden,
                          const float* __restrict__ cell,
                          const float* __restrict__ W_fc,
                          float* __restrict__ h, float* __restrict__ c,
                          _Float16* __restrict__ wfc16) {
    const int total = 32768 + 32768 + 131072;
    for (int i = blockIdx.x * 256 + threadIdx.x; i < total; i += gridDim.x * 256) {
        if (i < 32768)       h[i] = hidden[i];
        else if (i < 65536)  c[i - 32768] = cell[i - 32768];
        else                 wfc16[i - 65536] = (_Float16)W_fc[i - 65536];
    }
}

// One-time fp32 -> fp16 convert of encoder_outputs (33.5M elems, 8/thread).
__global__ void prep_ench(const float* __restrict__ enc,
                          _Float16* __restrict__ ench) {
    const size_t i = ((size_t)blockIdx.x * 256 + threadIdx.x) * 8;
    const float4 a = *(const float4*)(enc + i);
    const float4 b = *(const float4*)(enc + i + 4);
    hf8 o;
    o[0] = (_Float16)a.x; o[1] = (_Float16)a.y;
    o[2] = (_Float16)a.z; o[3] = (_Float16)a.w;
    o[4] = (_Float16)b.x; o[5] = (_Float16)b.y;
    o[6] = (_Float16)b.z; o[7] = (_Float16)b.w;
    *(hf8*)(ench + i) = o;
}

// FC for one (b, oq) unit; fp16 W_fc rows, fp32 accumulate (same order).
__device__ __forceinline__ void fc_unit(int v, int tprev,
                                        const float* __restrict__ h,
                                        const _Float16* __restrict__ wfc16,
                                        const float* __restrict__ b_fc,
                                        float* __restrict__ out,
                                        float (*shacc)[64]) {
    const int tid = threadIdx.x;
    const int b = v >> 2, oq = v & 3;
    const int ol = tid & 63, kq = tid >> 6;
    const int o = oq * 64 + ol;
    float acc = 0.f;
    const float* hp = h + b * HH + kq * 128;
    const _Float16* wp = wfc16 + (size_t)o * HH + kq * 128;
#pragma unroll 8
    for (int k2 = 0; k2 < 128; ++k2) acc += hp[k2] * (float)wp[k2];
    shacc[kq][ol] = acc;
    __syncthreads();
    if (tid < 64) {
        float vv = shacc[0][tid] + shacc[1][tid]
                 + shacc[2][tid] + shacc[3][tid] + b_fc[oq * 64 + tid];
        out[((size_t)b * TT + tprev) * OO + oq * 64 + tid] = vv;
    }
}

// K1: blocks 0..1023 attention partial (b, 64-row chunk) -> pm/pl/pctx(fp16);
// fdot2-based scores (fp16 h) + fp16-packed-p ctx accumulation (fp32 accum).
// ILP-4 groups. Blocks 1024..1279 FC(t-1). Fence-free.
__global__ void __launch_bounds__(256)
step_attnp(int t, const _Float16* __restrict__ ench,
           const float* __restrict__ h,
           float* __restrict__ pm, float* __restrict__ pl,
           _Float16* __restrict__ pctx,
           const _Float16* __restrict__ wfc16, const float* __restrict__ b_fc,
           float* __restrict__ out) {
    const int tid = threadIdx.x;
    const int lane = tid & 63;
    const int w = tid >> 6;

    __shared__ union {
        struct { float m[4]; float l[4]; float ctx[4][512]; } a;
        struct { float acc[4][64]; } o;
    } sh;

    const int u = blockIdx.x;
    if (u < 1024) {
        const int b = u >> 4, ch = u & 15;
        float m = -3.0e38f, l = 0.f;
        const float* hb = h + b * HH + lane * 8;
        h2 hp[4];
#pragma unroll
        for (int i = 0; i < 4; ++i)
            hp[i] = (h2){(_Float16)hb[2 * i], (_Float16)hb[2 * i + 1]};
        float cx[8];
#pragma unroll
        for (int j = 0; j < 8; ++j) cx[j] = 0.f;
        const _Float16* er =
            ench + ((size_t)(b * SS + ch * 64 + w * 16)) * HH + lane * 8;
        for (int g4 = 0; g4 < 4; ++g4) {
            const hf8 v0 = *(const hf8*)er;
            const hf8 v1 = *(const hf8*)(er + HH);
            const hf8 v2 = *(const hf8*)(er + 2 * HH);
            const hf8 v3 = *(const hf8*)(er + 3 * HH);
            const h2* q0 = (const h2*)&v0;
            const h2* q1 = (const h2*)&v1;
            const h2* q2 = (const h2*)&v2;
            const h2* q3 = (const h2*)&v3;
            float d0 = 0.f, d1 = 0.f, d2 = 0.f, d3 = 0.f;
#pragma unroll
            for (int i = 0; i < 4; ++i) {
                d0 = __builtin_amdgcn_fdot2(q0[i], hp[i], d0, false);
                d1 = __builtin_amdgcn_fdot2(q1[i], hp[i], d1, false);
                d2 = __builtin_amdgcn_fdot2(q2[i], hp[i], d2, false);
                d3 = __builtin_amdgcn_fdot2(q3[i], hp[i], d3, false);
            }
#pragma unroll
            for (int off = 32; off; off >>= 1) {
                d0 += __shfl_xor(d0, off);
                d1 += __shfl_xor(d1, off);
                d2 += __shfl_xor(d2, off);
                d3 += __shfl_xor(d3, off);
            }
            const float mx = fmaxf(fmaxf(d0, d1), fmaxf(d2, d3));
            if (mx > m) {                      // wave-uniform branch
                const float fs = __expf(m - mx);
                l *= fs;
#pragma unroll
                for (int j = 0; j < 8; ++j) cx[j] *= fs;
                m = mx;
            }
            const float p0 = __expf(d0 - m);
            const float p1 = __expf(d1 - m);
            const float p2 = __expf(d2 - m);
            const float p3 = __expf(d3 - m);
            l += (p0 + p1) + (p2 + p3);
            const h2 pk01 = (h2){(_Float16)p0, (_Float16)p1};
            const h2 pk23 = (h2){(_Float16)p2, (_Float16)p3};
#pragma unroll
            for (int j = 0; j < 8; ++j) {
                cx[j] = __builtin_amdgcn_fdot2((h2){v0[j], v1[j]}, pk01, cx[j], false);
                cx[j] = __builtin_amdgcn_fdot2((h2){v2[j], v3[j]}, pk23, cx[j], false);
            }
            er += 4 * HH;
        }
        if (lane == 0) { sh.a.m[w] = m; sh.a.l[w] = l; }
        *(float4*)&sh.a.ctx[w][lane * 8]     = make_float4(cx[0], cx[1], cx[2], cx[3]);
        *(float4*)&sh.a.ctx[w][lane * 8 + 4] = make_float4(cx[4], cx[5], cx[6], cx[7]);
        __syncthreads();
        // block-level combine of the 4 wave partials
        float M = fmaxf(fmaxf(sh.a.m[0], sh.a.m[1]), fmaxf(sh.a.m[2], sh.a.m[3]));
        float wg[4]; float ls = 0.f;
#pragma unroll
        for (int q = 0; q < 4; ++q) { wg[q] = __expf(sh.a.m[q] - M); ls += wg[q] * sh.a.l[q]; }
        const int hh = tid * 2;
        float v0 = wg[0] * sh.a.ctx[0][hh] + wg[1] * sh.a.ctx[1][hh]
                 + wg[2] * sh.a.ctx[2][hh] + wg[3] * sh.a.ctx[3][hh];
        float v1 = wg[0] * sh.a.ctx[0][hh + 1] + wg[1] * sh.a.ctx[1][hh + 1]
                 + wg[2] * sh.a.ctx[2][hh + 1] + wg[3] * sh.a.ctx[3][hh + 1];
        _Float16* pc = pctx + ((size_t)(b * 16 + ch)) * HH;
        pc[hh]     = (_Float16)v0;
        pc[hh + 1] = (_Float16)v1;
        if (tid == 0) { pm[b * 16 + ch] = M; pl[b * 16 + ch] = ls; }
    } else if (t > 0) {
        fc_unit(u - 1024, t - 1, h, wfc16, b_fc, out, sh.o.acc);
    }
}

// Fence-free combine, 128 blocks (b, half): merges 16 chunk partials (fp16
// pctx) -> xb hi/lo (bf16 split), packs target(t) and h. Same per-column
// summation order as R9/R15.
__global__ void __launch_bounds__(256)
step_combine(int t, const float* __restrict__ target, const float* __restrict__ h,
             const float* __restrict__ pm, const float* __restrict__ pl,
             const _Float16* __restrict__ pctx,
             ushort_t* __restrict__ xbh, ushort_t* __restrict__ xbl) {
    const int tid = threadIdx.x;
    const int b = blockIdx.x >> 1, hf = blockIdx.x & 1;
    float Mb = -3.0e38f;
#pragma unroll
    for (int q2 = 0; q2 < 16; ++q2) Mb = fmaxf(Mb, pm[b * 16 + q2]);
    float wq[16]; float lsb = 0.f;
#pragma unroll
    for (int q2 = 0; q2 < 16; ++q2) {
        wq[q2] = __expf(pm[b * 16 + q2] - Mb);
        lsb += wq[q2] * pl[b * 16 + q2];
    }
    const float inv = 1.0f / lsb;
    // ctx column col = hf*256 + tid
    const int col = hf * 256 + tid;
    float s = 0.f;
#pragma unroll
    for (int q2 = 0; q2 < 16; ++q2)
        s += wq[q2] * (float)pctx[((size_t)(b * 16 + q2)) * HH + col];
    s *= inv;
    const ushort_t a0 = f2bf(s);
    xbh[b * KK + col] = a0;
    xbl[b * KK + col] = f2bf(s - bf2f(a0));
    if (hf == 0) {
        // target packing: 256 cols
        const float tv = target[((size_t)b * TT + t) * OO + tid];
        const ushort_t t0 = f2bf(tv);
        xbh[b * KK + 512 + tid] = t0;
        xbl[b * KK + 512 + tid] = f2bf(tv - bf2f(t0));
    } else {
        // h packing: 512 cols, 2 per thread
        const int h2i = tid * 2;
        const float hv0 = h[b * HH + h2i], hv1 = h[b * HH + h2i + 1];
        const ushort_t g0 = f2bf(hv0), g1 = f2bf(hv1);
        xbh[b * KK + 768 + h2i]     = g0;
        xbl[b * KK + 768 + h2i]     = f2bf(hv0 - bf2f(g0));
        xbh[b * KK + 768 + h2i + 1] = g1;
        xbl[b * KK + 768 + h2i + 1] = f2bf(hv1 - bf2f(g1));
    }
}

// Gates, 128 blocks (bh, ht): split-bf16 MFMA (xh*Wh + xl*Wh + xh*Wl) over
// 32 b-rows per block + cell update. 2x CU coverage vs 64-block version.
__global__ void __launch_bounds__(256)
step_gates(const ushort_t* __restrict__ xbh,
           const ushort_t* __restrict__ xbl,
           const ushort_t* __restrict__ wfH,
           const ushort_t* __restrict__ wfL,
           const float* __restrict__ b_ih, const float* __restrict__ b_hh,
           float* __restrict__ h, float* __restrict__ c) {
    const int tid = threadIdx.x;
    const int lane = tid & 63;
    const int w = tid >> 6;
    __shared__ float g[32][32];

    const int bh = blockIdx.x >> 6;       // 0..1 : which 32-batch half
    const int ht = blockIdx.x & 63;
    const int nt = w >> 1;                // 0..1 : output 16-col tile
    fx4 a0 = {0, 0, 0, 0};
    const int bro = bh * 32 + 16 * (w & 1) + (lane & 15);
    const int kg = lane >> 4;
    const size_t wbase = (size_t)ht * 40 * 2 * 512;
    for (int kk = 0; kk < 40; ++kk) {
        const size_t aoff = (size_t)bro * KK + kk * 32 + kg * 8;
        bh8 avh = *(const bh8*)(xbh + aoff);
        bh8 avl = *(const bh8*)(xbl + aoff);
        bh8 bhv = *(const bh8*)(wfH + wbase + (kk * 2 + nt) * 512 + lane * 8);
        bh8 blv = *(const bh8*)(wfL + wbase + (kk * 2 + nt) * 512 + lane * 8);
        a0 = __builtin_amdgcn_mfma_f32_16x16x32_bf16(avh, bhv, a0, 0, 0, 0);
        a0 = __builtin_amdgcn_mfma_f32_16x16x32_bf16(avl, bhv, a0, 0, 0, 0);
        a0 = __builtin_amdgcn_mfma_f32_16x16x32_bf16(avh, blv, a0, 0, 0, 0);
    }
    const int crow = (lane >> 4) * 4;
#pragma unroll
    for (int r = 0; r < 4; ++r)
        g[16 * (w & 1) + crow + r][nt * 16 + (lane & 15)] = a0[r];
    __syncthreads();
    {
        const int lb = tid >> 3, r = tid & 7;     // local b 0..31, row 0..7
        const int b = bh * 32 + lb;
        const int hidx = ht * 8 + r;
        float gi = g[lb][r]      + b_ih[hidx]        + b_hh[hidx];
        float gf = g[lb][8 + r]  + b_ih[512 + hidx]  + b_hh[512 + hidx];
        float gg = g[lb][16 + r] + b_ih[1024 + hidx] + b_hh[1024 + hidx];
        float go = g[lb][24 + r] + b_ih[1536 + hidx] + b_hh[1536 + hidx];
        float ig = 1.f / (1.f + __expf(-gi));
        float fg = 1.f / (1.f + __expf(-gf));
        float g2 = tanhf(gg);
        float og = 1.f / (1.f + __expf(-go));
        float cn = fg * c[b * HH + hidx] + ig * g2;
        float hn = og * tanhf(cn);
        c[b * HH + hidx] = cn;
        h[b * HH + hidx] = hn;
    }
}

__global__ void __launch_bounds__(256)
fc_final(const float* __restrict__ h, const _Float16* __restrict__ wfc16,
         const float* __restrict__ b_fc, float* __restrict__ out) {
    __shared__ float acc[4][64];
    fc_unit(blockIdx.x, TT - 1, h, wfc16, b_fc, out, acc);
}

extern "C" void kernel_launch(void* const* d_in, const int* in_sizes, int n_in,
                              void* d_out, int out_size, void* d_ws, size_t ws_size,
                              hipStream_t stream) {
    const float* enc    = (const float*)d_in[0];
    const float* hidden = (const float*)d_in[1];
    const float* cellp  = (const float*)d_in[2];
    const float* target = (const float*)d_in[3];
    const float* W_ih   = (const float*)d_in[4];
    const float* W_hh   = (const float*)d_in[5];
    const float* b_ih   = (const float*)d_in[6];
    const float* b_hh   = (const float*)d_in[7];
    const float* W_fc   = (const float*)d_in[8];
    const float* b_fc   = (const float*)d_in[9];
    float* out = (float*)d_out;

    char* base = (char*)d_ws;
    float* h            = (float*)(base + 0);                  // 131,072 B
    float* c            = (float*)(base + 131072);             // 131,072 B
    ushort_t* wfH       = (ushort_t*)(base + 262144);          // 5,242,880 B
    ushort_t* wfL       = (ushort_t*)(base + 5505024);         // 5,242,880 B
    ushort_t* xbh       = (ushort_t*)(base + 10747904);        // 163,840 B
    ushort_t* xbl       = (ushort_t*)(base + 10911744);        // 163,840 B
    float* pm           = (float*)(base + 11075584);           // 4,096 B
    float* pl           = (float*)(base + 11079680);           // 4,096 B
    _Float16* wfc16     = (_Float16*)(base + 11083776);        // 262,144 B
    _Float16* pctx      = (_Float16*)(base + 11345920);        // 1,048,576 B
    _Float16* ench      = (_Float16*)(base + 12394496);        // 67,108,864 B
    // end: 79,503,360 B  (< 80,289,792 proven available)

    prep_weights<<<dim3(1280), dim3(256), 0, stream>>>(W_ih, W_hh, wfH, wfL);
    prep_misc<<<dim3(768), dim3(256), 0, stream>>>(hidden, cellp, W_fc, h, c, wfc16);
    prep_ench<<<dim3(16384), dim3(256), 0, stream>>>(enc, ench);

    for (int t = 0; t < TT; ++t) {
        step_attnp<<<dim3(1280), dim3(256), 0, stream>>>(
            t, ench, h, pm, pl, pctx, wfc16, b_fc, out);
        step_combine<<<dim3(128), dim3(256), 0, stream>>>(
            t, target, h, pm, pl, pctx, xbh, xbl);
        step_gates<<<dim3(128), dim3(256), 0, stream>>>(
            xbh, xbl, wfH, wfL, b_ih, b_hh, h, c);
    }
    fc_final<<<dim3(256), dim3(256), 0, stream>>>(h, wfc16, b_fc, out);
}